// Round 3
// baseline (1320.642 us; speedup 1.0000x reference)
//
#include <hip/hip_runtime.h>
#include <hip/hip_fp16.h>

// W8A16 GEMM: out[m,n] = (sum_k x[m,k]*w[n,k]) * scale[n] + bias[n]
// M=8192, K=4096, N=11008.
// Locked harness model (from absmax bit-pattern forensics r1-r3):
//   x: fp16 upcast to FLOAT32 [M,K]   (134 MB)
//   W: int8 widened to INT32  [N,K]   (180 MB)
//   scale, bias: float32 [N]
//   out: FLOAT32 [M,N]                (360 MB)
// Strategy: pre-convert x and W to fp16 in ws (both conversions EXACT), then a
// 256x256-tile 8-phase counted-vmcnt f16-MFMA GEMM (m201-lineage, T1+T2+T3/T4+T5),
// fp32 epilogue with scale+bias.
// R3 changes (vs R1=735us/45% best, R2=764us bundle regression):
//   - REVERT to R1-exact schedule: vmcnt(4) stage order, leading lgkmcnt(0) drain +
//     sched_barrier(0) before MFMA cluster (rule #18 / m201-exact)
//   - MFMA 16x16x32 -> 32x32x16 (ubench 2075->2382 TF ceiling, half the instr count);
//     same LDS, same staging, same region deps -> R1's RAW/WAR proof unchanged
//   - keep swapped operands (weights as operand-1) -> lane's 4 acc regs = 4 consecutive
//     n -> float4 scale/bias + global_store_dwordx4 epilogue

#define M_DIM 8192
#define K_DIM 4096
#define N_DIM 11008

// old (fallback) kernel tile params
#define TM 128
#define TN 128
#define BK 64
#define BKP 72

// new kernel grid params
#define MT_TILES 32              // 8192/256
#define NT_TILES 43              // 11008/256
#define NWG (MT_TILES * NT_TILES)  // 1376, % 8 == 0
#define CPX (NWG / 8)            // 172

typedef __attribute__((ext_vector_type(8))) _Float16 half8;   // 4 VGPRs
typedef __attribute__((ext_vector_type(4))) float floatx4;    // 16x16 MFMA acc (fallback)
typedef __attribute__((ext_vector_type(16))) float floatx16;  // 32x32 MFMA acc

union Pack16 { int4 i4; unsigned short u[8]; _Float16 h[8]; };

// ---------------- probe: widened int32 weights vs raw int8 bytes ----------------
__global__ __launch_bounds__(256) void probe_w(const int* __restrict__ W,
                                               unsigned int* __restrict__ f) {
    const size_t i0 = (size_t)blockIdx.x * 256 + threadIdx.x;
    const size_t stride = (size_t)gridDim.x * 256;
    int bad = 0;
    for (size_t i = i0; i < (size_t)(1u << 20); i += stride) {  // 4MB, in-bounds either way
        int w = W[i];
        if (w > 127 || w < -127) bad = 1;
    }
    if (bad) atomicOr(f, 1u);
}

// ---------------- x: fp32 -> fp16 (exact: values originate as fp16) ----------------
__global__ __launch_bounds__(256) void convert_x(const float* __restrict__ Xf,
                                                 unsigned short* __restrict__ Xh) {
    const size_t i = ((size_t)blockIdx.x * 256 + threadIdx.x) * 8;
    float4 a = *(const float4*)(Xf + i);
    float4 b = *(const float4*)(Xf + i + 4);
    Pack16 p;
    p.h[0] = (_Float16)a.x; p.h[1] = (_Float16)a.y;
    p.h[2] = (_Float16)a.z; p.h[3] = (_Float16)a.w;
    p.h[4] = (_Float16)b.x; p.h[5] = (_Float16)b.y;
    p.h[6] = (_Float16)b.z; p.h[7] = (_Float16)b.w;
    *(int4*)(Xh + i) = p.i4;
}

// ---------------- W: int32 (or raw int8 per flag) -> fp16 (exact, |v|<=127) ----------------
__global__ __launch_bounds__(256) void convert_w(const void* __restrict__ Wraw,
                                                 unsigned short* __restrict__ Wh,
                                                 const unsigned int* __restrict__ f) {
    const bool w8 = f[0] != 0u;
    const size_t i = ((size_t)blockIdx.x * 256 + threadIdx.x) * 8;  // weight index
    int v[8];
    if (w8) {
        int2 b = *(const int2*)((const char*)Wraw + i);
#pragma unroll
        for (int j = 0; j < 4; ++j)
            v[j] = (int)(signed char)(unsigned char)((((unsigned)b.x) >> (8 * j)) & 0xFFu);
#pragma unroll
        for (int j = 0; j < 4; ++j)
            v[4 + j] = (int)(signed char)(unsigned char)((((unsigned)b.y) >> (8 * j)) & 0xFFu);
    } else {
        const int4* src = (const int4*)((const int*)Wraw + i);
        int4 w0 = src[0], w1 = src[1];
        v[0] = w0.x; v[1] = w0.y; v[2] = w0.z; v[3] = w0.w;
        v[4] = w1.x; v[5] = w1.y; v[6] = w1.z; v[7] = w1.w;
    }
    Pack16 p;
#pragma unroll
    for (int j = 0; j < 8; ++j) p.h[j] = (_Float16)v[j];
    *(int4*)(Wh + i) = p.i4;
}

// ---------------- 8-phase 256x256 f16 MFMA GEMM (32x32x16) ----------------
// LDS: lds[dbuf][op(A=0,B=1)][khalf] of 256 rows x 32 f16 (16 KB blocks) = 128 KiB.
// Swizzle (both-sides involution within a 16KB block, rule #21):
//   phys_byte = logical_byte ^ ((row & 6) << 3)
// Staging: global_load_lds dwordx4, linear LDS dest, pre-swizzled global source.
// Stage unit = one [dbuf][op][khalf] region (2 gl16/thread = 16 KB).
// R1-exact schedule (iter i: read t0=2i from buf0 @p1-4, t1=2i+1 from buf1 @p5-8):
//   p1: stage A11(t1)  p2: B11(t1)  p3: A00(u0)  p4: B00(u0)+VM4
//   p5: stage A01(u0)  p6: B01(u0)  p7: A10(u1)  p8: B10(u1)+VM4
// Prologue: 6 units (t0 all + t1.kh0), vmcnt(4). Peel: A11/B11(63) @p1/p2, VM0 @p4.
// MFMA: v_mfma_f32_32x32x16_f16, swapped operands (B first). Per phase:
//   2 m-subtiles x 2 n-subtiles x 2 ksteps = 8 MFMA; frag = half8 (free=lane&31,
//   k=(lane>>5)*8+j). C layout (m74/m101, swapped): m=lane&31,
//   n=8*(reg>>2)+4*(lane>>5)+(reg&3) -> reg&3 fastest = float4 over n.

__device__ __forceinline__ void gl16(const void* g, void* l) {
    __builtin_amdgcn_global_load_lds(
        (const __attribute__((address_space(1))) unsigned int*)g,
        (__attribute__((address_space(3))) unsigned int*)l, 16, 0, 0);
}

__global__ __launch_bounds__(512, 2) void w8a16_gemm_8ph(
    const unsigned short* __restrict__ Xh, const unsigned short* __restrict__ Wh,
    const float* __restrict__ scale, const float* __restrict__ bias,
    float* __restrict__ Out)
{
    __shared__ unsigned char lds[2][2][2][16384];  // [dbuf][A/B][khalf] 128 KiB

    const int t = threadIdx.x;       // 0..511
    const int lane = t & 63;
    const int wv = t >> 6;           // 0..7
    const int wr = wv >> 2;          // 0..1  (M)
    const int wc = wv & 3;           // 0..3  (N)
    const int fr32 = lane & 31;      // 32x32 fragment free index
    const int h = lane >> 5;         // k-half of fragment (0/1)

    // T1: bijective XCD swizzle (1376 % 8 == 0), nt-fastest for A-panel L2 reuse
    const int bid = blockIdx.x;
    const int swz = (bid & 7) * CPX + (bid >> 3);
    const int mt = swz / NT_TILES;
    const int nt = swz - mt * NT_TILES;
    const size_t tileM = (size_t)mt << 8;
    const size_t tileN = (size_t)nt << 8;

    // --- stage source addressing (per thread, pre-swizzled global column) ---
    const int rr = t >> 2;  // 0..127 (j adds 128)
    const int cA = ((((t & 3) << 4) ^ (((t >> 2) & 6) << 3)) >> 1);  // 0..31
    const unsigned short* srcA0 = Xh + (tileM + rr) * K_DIM + cA;
    const unsigned short* srcA1 = srcA0 + (size_t)128 * K_DIM;
    const unsigned short* srcB0 = Wh + (tileN + rr) * K_DIM + cA;
    const unsigned short* srcB1 = srcB0 + (size_t)128 * K_DIM;
    const int wvofs = wv << 10;  // wave-uniform LDS byte base within a 16KB block

    // --- ds_read fragment bases (byte offset in a 16KB block, swizzled) ---
    // row = base_row + fr32; base_row offsets (wr*128, wc*64, mg*64, m*32) are
    // multiples of 8 -> (row&6) == (fr32&6) -> swizzle is a per-lane constant.
    // col = kk*32 + h*16; phys = row*64 + (col ^ swz). kk handled by second base
    // (rd^32 valid: h*16 has bit5 clear, swz only has bits 4-5).
    const int gswz = (fr32 & 6) << 3;
    const int rdA  = (((wr << 7) + fr32) << 6) + ((h << 4) ^ gswz);  // kk=0
    const int rdA2 = rdA ^ 32;                                      // kk=1
    const int rdB  = (((wc << 6) + fr32) << 6) + ((h << 4) ^ gswz);
    const int rdB2 = rdB ^ 32;

    floatx16 acc[4][2];  // [m-subtile][n-subtile], 128 VGPR
#pragma unroll
    for (int m = 0; m < 4; ++m)
#pragma unroll
        for (int n = 0; n < 2; ++n)
            acc[m][n] = (floatx16){0.f,0.f,0.f,0.f,0.f,0.f,0.f,0.f,
                                   0.f,0.f,0.f,0.f,0.f,0.f,0.f,0.f};

    half8 afr[2][2], bfr[2][2];  // [subtile][kstep]

#define STAGE_A(d_, kh_, tau_) do { \
    const unsigned short* _g0 = srcA0 + ((tau_) * 64 + (kh_) * 32); \
    const unsigned short* _g1 = srcA1 + ((tau_) * 64 + (kh_) * 32); \
    unsigned char* _l = &lds[d_][0][kh_][0] + wvofs; \
    gl16(_g0, _l); gl16(_g1, _l + 8192); \
} while (0)

#define STAGE_B(d_, kh_, tau_) do { \
    const unsigned short* _g0 = srcB0 + ((tau_) * 64 + (kh_) * 32); \
    const unsigned short* _g1 = srcB1 + ((tau_) * 64 + (kh_) * 32); \
    unsigned char* _l = &lds[d_][1][kh_][0] + wvofs; \
    gl16(_g0, _l); gl16(_g1, _l + 8192); \
} while (0)

#define VM4 asm volatile("s_waitcnt vmcnt(4)" ::: "memory")
#define VM0 asm volatile("s_waitcnt vmcnt(0)" ::: "memory")
#define NOSTG ((void)0)

#define PHASE(d_, kh_, mg_, RB_, STG_, VM_) do { \
    const unsigned char* _Ab = &lds[d_][0][kh_][0]; \
    const unsigned char* _Bb = &lds[d_][1][kh_][0]; \
    if (RB_) { \
        _Pragma("unroll") \
        for (int _n = 0; _n < 2; ++_n) { \
            bfr[_n][0] = *(const half8*)(const void*)(_Bb + rdB  + _n * 2048); \
            bfr[_n][1] = *(const half8*)(const void*)(_Bb + rdB2 + _n * 2048); \
        } \
    } \
    _Pragma("unroll") \
    for (int _m = 0; _m < 2; ++_m) { \
        afr[_m][0] = *(const half8*)(const void*)(_Ab + rdA  + (mg_) * 4096 + _m * 2048); \
        afr[_m][1] = *(const half8*)(const void*)(_Ab + rdA2 + (mg_) * 4096 + _m * 2048); \
    } \
    STG_; \
    VM_; \
    asm volatile("s_barrier" ::: "memory"); \
    asm volatile("s_waitcnt lgkmcnt(0)" ::: "memory"); \
    __builtin_amdgcn_sched_barrier(0); \
    __builtin_amdgcn_s_setprio(1); \
    _Pragma("unroll") \
    for (int _m = 0; _m < 2; ++_m) \
        _Pragma("unroll") \
        for (int _n = 0; _n < 2; ++_n) \
            _Pragma("unroll") \
            for (int _k = 0; _k < 2; ++_k) \
                acc[(mg_) * 2 + _m][_n] = __builtin_amdgcn_mfma_f32_32x32x16_f16( \
                    bfr[_n][_k], afr[_m][_k], acc[(mg_) * 2 + _m][_n], 0, 0, 0); \
    __builtin_amdgcn_s_setprio(0); \
    asm volatile("s_barrier" ::: "memory"); \
} while (0)

    // prologue: 6 stage units (t0: A00,B00,A01,B01; t1: A10,B10), vmcnt(4)
    // confirms the 4 t0 units, leaves {A10,B10} in flight.
    STAGE_A(0, 0, 0); STAGE_B(0, 0, 0); STAGE_A(0, 1, 0); STAGE_B(0, 1, 0);
    STAGE_A(1, 0, 1); STAGE_B(1, 0, 1);
    asm volatile("s_waitcnt vmcnt(4)" ::: "memory");
    asm volatile("s_barrier" ::: "memory");

#pragma unroll 1
    for (int i = 0; i < 31; ++i) {
        const int t1 = 2 * i + 1, u0 = 2 * i + 2, u1 = 2 * i + 3;
        PHASE(0, 0, 0, 1, STAGE_A(1, 1, t1), NOSTG);
        PHASE(0, 0, 1, 0, STAGE_B(1, 1, t1), NOSTG);
        PHASE(0, 1, 0, 1, STAGE_A(0, 0, u0), NOSTG);
        PHASE(0, 1, 1, 0, STAGE_B(0, 0, u0), VM4);
        PHASE(1, 0, 0, 1, STAGE_A(0, 1, u0), NOSTG);
        PHASE(1, 0, 1, 0, STAGE_B(0, 1, u0), NOSTG);
        PHASE(1, 1, 0, 1, STAGE_A(1, 0, u1), NOSTG);
        PHASE(1, 1, 1, 0, STAGE_B(1, 0, u1), VM4);
    }
    // peeled last iteration: reads t62 (buf0), t63 (buf1); only A11/B11(63) to stage.
    PHASE(0, 0, 0, 1, STAGE_A(1, 1, 63), NOSTG);
    PHASE(0, 0, 1, 0, STAGE_B(1, 1, 63), NOSTG);
    PHASE(0, 1, 0, 1, NOSTG, NOSTG);
    PHASE(0, 1, 1, 0, NOSTG, VM0);
    PHASE(1, 0, 0, 1, NOSTG, NOSTG);
    PHASE(1, 0, 1, 0, NOSTG, NOSTG);
    PHASE(1, 1, 0, 1, NOSTG, NOSTG);
    PHASE(1, 1, 1, 0, NOSTG, NOSTG);

#undef PHASE
#undef STAGE_A
#undef STAGE_B
#undef VM4
#undef VM0
#undef NOSTG

    // epilogue (swapped-operand 32x32 C layout): m = lane&31,
    // n = ntt*32 + 8*(reg>>2) + 4*h + (reg&3) -> float4 stores over reg&3.
    const int h4 = h << 2;
#pragma unroll
    for (int mt2 = 0; mt2 < 4; ++mt2) {
        const size_t m = tileM + (size_t)((wr << 7) + (mt2 << 5) + fr32);
        float* orow = Out + m * N_DIM;
#pragma unroll
        for (int ntt = 0; ntt < 2; ++ntt) {
#pragma unroll
            for (int g = 0; g < 4; ++g) {
                const int nb = (int)tileN + (wc << 6) + (ntt << 5) + (g << 3) + h4;
                const float4 s4 = *(const float4*)(scale + nb);
                const float4 b4 = *(const float4*)(bias + nb);
                float4 o;
                o.x = acc[mt2][ntt][g * 4 + 0] * s4.x + b4.x;
                o.y = acc[mt2][ntt][g * 4 + 1] * s4.y + b4.y;
                o.z = acc[mt2][ntt][g * 4 + 2] * s4.z + b4.z;
                o.w = acc[mt2][ntt][g * 4 + 3] * s4.w + b4.w;
                *(float4*)(orow + nb) = o;
            }
        }
    }
}

// ---------------- fallback GEMM (old 128x128, inline/partial convert) ----------------
template <bool XPRE, bool WPRE>
__global__ __launch_bounds__(256) void w8a16_gemm(
    const float* __restrict__ Xf, const unsigned short* __restrict__ Xh,
    const int* __restrict__ Wi, const unsigned short* __restrict__ Wh,
    const float* __restrict__ scale, const float* __restrict__ bias,
    float* __restrict__ Out)
{
    __shared__ unsigned short As[TM * BKP];
    __shared__ unsigned short Bs[TN * BKP];

    const int t = threadIdx.x;
    const int lane = t & 63;
    const int wave = t >> 6;
    const int tileM = blockIdx.y * TM;
    const int tileN = blockIdx.x * TN;
    const int wm = (wave & 1) * 64;
    const int wn = (wave >> 1) * 64;
    const int fr = lane & 15;
    const int fk = (lane >> 4) * 8;

    floatx4 acc[4][4];
#pragma unroll
    for (int mi = 0; mi < 4; ++mi)
#pragma unroll
        for (int ni = 0; ni < 4; ++ni) acc[mi][ni] = (floatx4){0.f, 0.f, 0.f, 0.f};

    for (int k0 = 0; k0 < K_DIM; k0 += BK) {
#pragma unroll
        for (int it = 0; it < 4; ++it) {
            const int c = it * 256 + t;
            const int r = c >> 3;
            const int qq = c & 7;
            if (XPRE) {
                *(int4*)(As + r * BKP + qq * 8) =
                    *(const int4*)(Xh + (size_t)(tileM + r) * K_DIM + k0 + qq * 8);
            } else {
                const float* s = Xf + (size_t)(tileM + r) * K_DIM + k0 + qq * 8;
                float4 x0 = ((const float4*)s)[0];
                float4 x1 = ((const float4*)s)[1];
                Pack16 p;
                p.h[0] = (_Float16)x0.x; p.h[1] = (_Float16)x0.y;
                p.h[2] = (_Float16)x0.z; p.h[3] = (_Float16)x0.w;
                p.h[4] = (_Float16)x1.x; p.h[5] = (_Float16)x1.y;
                p.h[6] = (_Float16)x1.z; p.h[7] = (_Float16)x1.w;
                *(int4*)(As + r * BKP + qq * 8) = p.i4;
            }
            if (WPRE) {
                *(int4*)(Bs + r * BKP + qq * 8) =
                    *(const int4*)(Wh + (size_t)(tileN + r) * K_DIM + k0 + qq * 8);
            } else {
                const int* s = Wi + (size_t)(tileN + r) * K_DIM + k0 + qq * 8;
                int4 w0 = ((const int4*)s)[0];
                int4 w1 = ((const int4*)s)[1];
                Pack16 p;
                p.h[0] = (_Float16)w0.x; p.h[1] = (_Float16)w0.y;
                p.h[2] = (_Float16)w0.z; p.h[3] = (_Float16)w0.w;
                p.h[4] = (_Float16)w1.x; p.h[5] = (_Float16)w1.y;
                p.h[6] = (_Float16)w1.z; p.h[7] = (_Float16)w1.w;
                *(int4*)(Bs + r * BKP + qq * 8) = p.i4;
            }
        }
        __syncthreads();
#pragma unroll
        for (int kh = 0; kh < 2; ++kh) {
            half8 a[4], b[4];
#pragma unroll
            for (int i = 0; i < 4; ++i)
                a[i] = *(const half8*)(const void*)(As + (wm + i * 16 + fr) * BKP + kh * 32 + fk);
#pragma unroll
            for (int i = 0; i < 4; ++i)
                b[i] = *(const half8*)(const void*)(Bs + (wn + i * 16 + fr) * BKP + kh * 32 + fk);
#pragma unroll
            for (int mi = 0; mi < 4; ++mi)
#pragma unroll
                for (int ni = 0; ni < 4; ++ni)
                    acc[mi][ni] = __builtin_amdgcn_mfma_f32_16x16x32_f16(
                        a[mi], b[ni], acc[mi][ni], 0, 0, 0);
        }
        __syncthreads();
    }

    const int rbase = (lane >> 4) * 4;
#pragma unroll
    for (int ni = 0; ni < 4; ++ni) {
        const int n = tileN + wn + ni * 16 + fr;
        const float s = scale[n];
        const float bz = bias[n];
#pragma unroll
        for (int mi = 0; mi < 4; ++mi) {
            const int m = tileM + wm + mi * 16 + rbase;
#pragma unroll
            for (int r = 0; r < 4; ++r)
                Out[(size_t)(m + r) * N_DIM + n] = acc[mi][ni][r] * s + bz;
        }
    }
}

extern "C" void kernel_launch(void* const* d_in, const int* in_sizes, int n_in,
                              void* d_out, int out_size, void* d_ws, size_t ws_size,
                              hipStream_t stream) {
    // --- resolve inputs BY SIZE (robust to pytree vs insertion ordering) ---
    const long long SZ_X = (long long)M_DIM * K_DIM;  // 33,554,432
    const long long SZ_W = (long long)N_DIM * K_DIM;  // 45,088,768
    const void *pX = nullptr, *pW = nullptr, *pS = nullptr, *pB = nullptr;
    int smallIdx[8];
    int nSmall = 0;
    for (int i = 0; i < n_in; ++i) {
        long long s = in_sizes[i];
        if (s == SZ_X && !pX) pX = d_in[i];
        else if (s == SZ_W && !pW) pW = d_in[i];
        else if (s == (long long)N_DIM && nSmall < 8) smallIdx[nSmall++] = i;
    }
    if (nSmall == 2) {
        if (smallIdx[0] == 2)      { pS = d_in[2]; pB = d_in[smallIdx[1]]; }
        else if (smallIdx[1] == 2) { pS = d_in[2]; pB = d_in[smallIdx[0]]; }
        else                       { pS = d_in[smallIdx[0]]; pB = d_in[smallIdx[1]]; }
    }
    if (!pX || !pW || !pS || !pB) { pX = d_in[0]; pW = d_in[1]; pS = d_in[2]; pB = d_in[3]; }

    const float* Xf = (const float*)pX;
    const int* Wi = (const int*)pW;
    const float* scale = (const float*)pS;
    const float* bias = (const float*)pB;
    float* Out = (float*)d_out;

    dim3 gridOld(N_DIM / TN, M_DIM / TM);  // 86 x 64
    const size_t OFF = 256;
    const size_t XH_BYTES = (size_t)SZ_X * 2;  // 67 MB fp16 x
    const size_t WH_BYTES = (size_t)SZ_W * 2;  // 90 MB fp16 w

    if (ws_size >= OFF + XH_BYTES + WH_BYTES + 64) {
        unsigned int* flags = (unsigned int*)d_ws;
        unsigned short* Xh = (unsigned short*)((char*)d_ws + OFF);
        unsigned short* Wh = (unsigned short*)((char*)d_ws + OFF + XH_BYTES);
        hipMemsetAsync(flags, 0, 4, stream);
        probe_w<<<256, 256, 0, stream>>>(Wi, flags);
        convert_x<<<(int)(SZ_X / 8 / 256), 256, 0, stream>>>(Xf, Xh);
        convert_w<<<(int)(SZ_W / 8 / 256), 256, 0, stream>>>(pW, Wh, flags);
        w8a16_gemm_8ph<<<dim3(NWG), dim3(512), 0, stream>>>(Xh, Wh, scale, bias, Out);
    } else if (ws_size >= OFF + WH_BYTES + 64) {
        unsigned int* flags = (unsigned int*)d_ws;
        unsigned short* Wh = (unsigned short*)((char*)d_ws + OFF);
        hipMemsetAsync(flags, 0, 4, stream);
        probe_w<<<256, 256, 0, stream>>>(Wi, flags);
        convert_w<<<(int)(SZ_W / 8 / 256), 256, 0, stream>>>(pW, Wh, flags);
        w8a16_gemm<false, true><<<gridOld, 256, 0, stream>>>(Xf, nullptr, Wi, Wh, scale, bias, Out);
    } else {
        w8a16_gemm<false, false><<<gridOld, 256, 0, stream>>>(Xf, nullptr, Wi, nullptr, scale, bias, Out);
    }
}

// Round 4
// 1233.927 us; speedup vs baseline: 1.0703x; 1.0703x over previous
//
#include <hip/hip_runtime.h>
#include <hip/hip_fp16.h>

// W8A16 GEMM: out[m,n] = (sum_k x[m,k]*w[n,k]) * scale[n] + bias[n]
// M=8192, K=4096, N=11008.
// Locked harness model (from absmax bit-pattern forensics r1-r3):
//   x: fp16 upcast to FLOAT32 [M,K]   (134 MB)
//   W: int8 widened to INT32  [N,K]   (180 MB)
//   scale, bias: float32 [N]
//   out: FLOAT32 [M,N]                (360 MB)
// Strategy: pre-convert x and W to fp16 in ws (both conversions EXACT), then a
// 256x256-tile 8-phase counted-vmcnt f16-MFMA GEMM (m201-lineage), fp32 epilogue.
// History: R1(=round0 kernel) 735us MfmaUtil 45 conflicts 0 (BEST).
//          R2 764us (bundle: vmcnt6+no-drain+swapped epi) REGRESSED.
//          R3 850us (32x32 MFMA) -> 6.8e7 bank conflicts, REVERTED.
// R4 change (single variable vs R1): READ-AHEAD-ONE-PHASE. Phase p issues phase
// p+1's ds_reads into a second fragment register set right after barrier1, then
// waits counted lgkmcnt(N_just_issued) instead of lgkmcnt(0). LDS service of the
// reads overlaps the MFMA section + barriers instead of serializing before them.
// Stage order, VM4 points, MFMA shape, epilogue: R1-identical.

#define M_DIM 8192
#define K_DIM 4096
#define N_DIM 11008

// old (fallback) kernel tile params
#define TM 128
#define TN 128
#define BK 64
#define BKP 72

// new kernel grid params
#define MT_TILES 32              // 8192/256
#define NT_TILES 43              // 11008/256
#define NWG (MT_TILES * NT_TILES)  // 1376, % 8 == 0
#define CPX (NWG / 8)            // 172

typedef __attribute__((ext_vector_type(8))) _Float16 half8;  // 4 VGPRs
typedef __attribute__((ext_vector_type(4))) float floatx4;   // MFMA acc

union Pack16 { int4 i4; unsigned short u[8]; _Float16 h[8]; };

// ---------------- probe: widened int32 weights vs raw int8 bytes ----------------
__global__ __launch_bounds__(256) void probe_w(const int* __restrict__ W,
                                               unsigned int* __restrict__ f) {
    const size_t i0 = (size_t)blockIdx.x * 256 + threadIdx.x;
    const size_t stride = (size_t)gridDim.x * 256;
    int bad = 0;
    for (size_t i = i0; i < (size_t)(1u << 20); i += stride) {  // 4MB, in-bounds either way
        int w = W[i];
        if (w > 127 || w < -127) bad = 1;
    }
    if (bad) atomicOr(f, 1u);
}

// ---------------- x: fp32 -> fp16 (exact: values originate as fp16) ----------------
__global__ __launch_bounds__(256) void convert_x(const float* __restrict__ Xf,
                                                 unsigned short* __restrict__ Xh) {
    const size_t i = ((size_t)blockIdx.x * 256 + threadIdx.x) * 8;
    float4 a = *(const float4*)(Xf + i);
    float4 b = *(const float4*)(Xf + i + 4);
    Pack16 p;
    p.h[0] = (_Float16)a.x; p.h[1] = (_Float16)a.y;
    p.h[2] = (_Float16)a.z; p.h[3] = (_Float16)a.w;
    p.h[4] = (_Float16)b.x; p.h[5] = (_Float16)b.y;
    p.h[6] = (_Float16)b.z; p.h[7] = (_Float16)b.w;
    *(int4*)(Xh + i) = p.i4;
}

// ---------------- W: int32 (or raw int8 per flag) -> fp16 (exact, |v|<=127) ----------------
__global__ __launch_bounds__(256) void convert_w(const void* __restrict__ Wraw,
                                                 unsigned short* __restrict__ Wh,
                                                 const unsigned int* __restrict__ f) {
    const bool w8 = f[0] != 0u;
    const size_t i = ((size_t)blockIdx.x * 256 + threadIdx.x) * 8;  // weight index
    int v[8];
    if (w8) {
        int2 b = *(const int2*)((const char*)Wraw + i);
#pragma unroll
        for (int j = 0; j < 4; ++j)
            v[j] = (int)(signed char)(unsigned char)((((unsigned)b.x) >> (8 * j)) & 0xFFu);
#pragma unroll
        for (int j = 0; j < 4; ++j)
            v[4 + j] = (int)(signed char)(unsigned char)((((unsigned)b.y) >> (8 * j)) & 0xFFu);
    } else {
        const int4* src = (const int4*)((const int*)Wraw + i);
        int4 w0 = src[0], w1 = src[1];
        v[0] = w0.x; v[1] = w0.y; v[2] = w0.z; v[3] = w0.w;
        v[4] = w1.x; v[5] = w1.y; v[6] = w1.z; v[7] = w1.w;
    }
    Pack16 p;
#pragma unroll
    for (int j = 0; j < 8; ++j) p.h[j] = (_Float16)v[j];
    *(int4*)(Wh + i) = p.i4;
}

// ---------------- 8-phase 256x256 f16 MFMA GEMM (read-ahead) ----------------
// LDS: lds[dbuf][op(A=0,B=1)][khalf] of 256 rows x 32 f16 (16 KB blocks) = 128 KiB.
// Swizzle: phys_byte = logical_byte ^ ((row & 6) << 3) (16-row-span reads: 0 conflicts, R1-measured).
// Stage schedule (R1-exact): p1 A11(t1) p2 B11(t1) p3 A00(u0) p4 B00(u0)+VM4
//                            p5 A01(u0) p6 B01(u0) p7 A10(u1) p8 B10(u1)+VM4
// Read-ahead: phase p issues reads for phase p+1 after barrier1, waits lgkmcnt(N)
// (N = count just issued: 4 on A-only phases, 8 on A+B), then MFMAs phase p's frags.
// A-frag sets alternate every phase (a1 consumed on odd phases, a0 on even);
// B-frag sets alternate every 2 phases (b0f on p1/p2/p5/p6, b1f on p3/p4/p7/p8).
// Staged-data visibility for read-issues: p1-next reads A00/B00 at p8 after VM4@p8;
// p5 reads A10/B10 at p4 after VM4@p4; p3/p7 regions confirmed >=1 VM point earlier.
// WAR: stage@q issues only after barrier2(q-1); all reads complete before each
// wave's counted wait, which precedes its barrier2. Peel: A11/B11(63)@p1/p2, VM0@p4,
// p8 issues no reads -> lgkmcnt(0).

__device__ __forceinline__ void gl16(const void* g, void* l) {
    __builtin_amdgcn_global_load_lds(
        (const __attribute__((address_space(1))) unsigned int*)g,
        (__attribute__((address_space(3))) unsigned int*)l, 16, 0, 0);
}

__global__ __launch_bounds__(512, 2) void w8a16_gemm_8ph(
    const unsigned short* __restrict__ Xh, const unsigned short* __restrict__ Wh,
    const float* __restrict__ scale, const float* __restrict__ bias,
    float* __restrict__ Out)
{
    __shared__ unsigned char lds[2][2][2][16384];  // [dbuf][A/B][khalf] 128 KiB

    const int t = threadIdx.x;       // 0..511
    const int lane = t & 63;
    const int wv = t >> 6;           // 0..7
    const int wr = wv >> 2;          // 0..1  (M)
    const int wc = wv & 3;           // 0..3  (N)
    const int fr = lane & 15;        // fragment free index
    const int q  = lane >> 4;        // fragment k-quad

    // T1: bijective XCD swizzle (1376 % 8 == 0), nt-fastest for A-panel L2 reuse
    const int bid = blockIdx.x;
    const int swz = (bid & 7) * CPX + (bid >> 3);
    const int mt = swz / NT_TILES;
    const int nt = swz - mt * NT_TILES;
    const size_t tileM = (size_t)mt << 8;
    const size_t tileN = (size_t)nt << 8;

    // --- stage source addressing (per thread, pre-swizzled global column) ---
    const int rr = t >> 2;  // 0..127 (j adds 128)
    const int cA = ((((t & 3) << 4) ^ (((t >> 2) & 6) << 3)) >> 1);  // 0..31
    const unsigned short* srcA0 = Xh + (tileM + rr) * K_DIM + cA;
    const unsigned short* srcA1 = srcA0 + (size_t)128 * K_DIM;
    const unsigned short* srcB0 = Wh + (tileN + rr) * K_DIM + cA;
    const unsigned short* srcB1 = srcB0 + (size_t)128 * K_DIM;
    const int wvofs = wv << 10;  // wave-uniform LDS byte base within a 16KB block

    // --- ds_read fragment bases (byte offset in a 16KB block, swizzled) ---
    const int gsw = (fr & 6) << 3;
    const int rdA = ((((wr << 7) + fr) << 6) + (q << 4)) ^ gsw;
    const int rdB = ((((wc << 6) + fr) << 6) + (q << 4)) ^ gsw;

    floatx4 acc[8][4];
#pragma unroll
    for (int m = 0; m < 8; ++m)
#pragma unroll
        for (int n = 0; n < 4; ++n) acc[m][n] = (floatx4){0.f, 0.f, 0.f, 0.f};

    // double-buffered fragment register sets (static names, rule #20)
    half8 a0[4], a1[4], b0f[4], b1f[4];

#define STAGE_A(d_, kh_, tau_) do { \
    const unsigned short* _g0 = srcA0 + ((tau_) * 64 + (kh_) * 32); \
    const unsigned short* _g1 = srcA1 + ((tau_) * 64 + (kh_) * 32); \
    unsigned char* _l = &lds[d_][0][kh_][0] + wvofs; \
    gl16(_g0, _l); gl16(_g1, _l + 8192); \
} while (0)

#define STAGE_B(d_, kh_, tau_) do { \
    const unsigned short* _g0 = srcB0 + ((tau_) * 64 + (kh_) * 32); \
    const unsigned short* _g1 = srcB1 + ((tau_) * 64 + (kh_) * 32); \
    unsigned char* _l = &lds[d_][1][kh_][0] + wvofs; \
    gl16(_g0, _l); gl16(_g1, _l + 8192); \
} while (0)

#define VM4 asm volatile("s_waitcnt vmcnt(4)" ::: "memory")
#define VM0 asm volatile("s_waitcnt vmcnt(0)" ::: "memory")
#define BAR asm volatile("s_barrier" ::: "memory")
#define NOSTG ((void)0)

// issue ds_reads for a phase's fragments into the given register sets
#define RD(d_, kh_, mg_, RB_, A_, B_) do { \
    const unsigned char* _Ab = &lds[d_][0][kh_][0]; \
    if (RB_) { \
        const unsigned char* _Bb = &lds[d_][1][kh_][0]; \
        _Pragma("unroll") \
        for (int _n = 0; _n < 4; ++_n) \
            B_[_n] = *(const half8*)(const void*)(_Bb + rdB + _n * 1024); \
    } \
    _Pragma("unroll") \
    for (int _m = 0; _m < 4; ++_m) \
        A_[_m] = *(const half8*)(const void*)(_Ab + rdA + (mg_) * 4096 + _m * 1024); \
} while (0)

// counted lgkm wait + scheduler fence (rule #18)
#define LG(n_) do { \
    asm volatile("s_waitcnt lgkmcnt(" #n_ ")" ::: "memory"); \
    __builtin_amdgcn_sched_barrier(0); \
} while (0)

#define MM(mg_, A_, B_) do { \
    __builtin_amdgcn_s_setprio(1); \
    _Pragma("unroll") \
    for (int _m = 0; _m < 4; ++_m) \
        _Pragma("unroll") \
        for (int _n = 0; _n < 4; ++_n) \
            acc[(mg_) * 4 + _m][_n] = __builtin_amdgcn_mfma_f32_16x16x32_f16( \
                A_[_m], B_[_n], acc[(mg_) * 4 + _m][_n], 0, 0, 0); \
    __builtin_amdgcn_s_setprio(0); \
} while (0)

    // prologue: 6 stage units (t0: A00,B00,A01,B01; t1: A10,B10), vmcnt(4)
    // confirms the 4 t0 units, leaves {A10,B10} in flight. Then pre-issue the
    // reads for p1 (A00/B00 -> a1,b0f; both confirmed).
    STAGE_A(0, 0, 0); STAGE_B(0, 0, 0); STAGE_A(0, 1, 0); STAGE_B(0, 1, 0);
    STAGE_A(1, 0, 1); STAGE_B(1, 0, 1);
    asm volatile("s_waitcnt vmcnt(4)" ::: "memory");
    BAR;
    RD(0, 0, 0, 1, a1, b0f);

#pragma unroll 1
    for (int i = 0; i < 31; ++i) {
        const int t1 = 2 * i + 1, u0 = 2 * i + 2, u1 = 2 * i + 3;
        // p1: consume (b0,kh0,mg0) [a1,b0f]; read p2 (A->a0)
        STAGE_A(1, 1, t1); BAR; RD(0, 0, 1, 0, a0, b0f); LG(4); MM(0, a1, b0f); BAR;
        // p2: consume (b0,kh0,mg1) [a0,b0f]; read p3 (A->a1, B->b1f)
        STAGE_B(1, 1, t1); BAR; RD(0, 1, 0, 1, a1, b1f); LG(8); MM(1, a0, b0f); BAR;
        // p3: consume (b0,kh1,mg0) [a1,b1f]; read p4 (A->a0)
        STAGE_A(0, 0, u0); BAR; RD(0, 1, 1, 0, a0, b1f); LG(4); MM(0, a1, b1f); BAR;
        // p4: consume (b0,kh1,mg1) [a0,b1f]; VM4; read p5 (A->a1, B->b0f)
        STAGE_B(0, 0, u0); VM4; BAR; RD(1, 0, 0, 1, a1, b0f); LG(8); MM(1, a0, b1f); BAR;
        // p5: consume (b1,kh0,mg0) [a1,b0f]; read p6 (A->a0)
        STAGE_A(0, 1, u0); BAR; RD(1, 0, 1, 0, a0, b0f); LG(4); MM(0, a1, b0f); BAR;
        // p6: consume (b1,kh0,mg1) [a0,b0f]; read p7 (A->a1, B->b1f)
        STAGE_B(0, 1, u0); BAR; RD(1, 1, 0, 1, a1, b1f); LG(8); MM(1, a0, b0f); BAR;
        // p7: consume (b1,kh1,mg0) [a1,b1f]; read p8 (A->a0)
        STAGE_A(1, 0, u1); BAR; RD(1, 1, 1, 0, a0, b1f); LG(4); MM(0, a1, b1f); BAR;
        // p8: consume (b1,kh1,mg1) [a0,b1f]; VM4; read next-p1 (A->a1, B->b0f)
        STAGE_B(1, 0, u1); VM4; BAR; RD(0, 0, 0, 1, a1, b0f); LG(8); MM(1, a0, b1f); BAR;
    }
    // peeled last iteration: reads t62 (buf0), t63 (buf1); only A11/B11(63) staged.
    STAGE_A(1, 1, 63); BAR; RD(0, 0, 1, 0, a0, b0f); LG(4); MM(0, a1, b0f); BAR;
    STAGE_B(1, 1, 63); BAR; RD(0, 1, 0, 1, a1, b1f); LG(8); MM(1, a0, b0f); BAR;
    BAR_SPLIT_P3: ;
    BAR; RD(0, 1, 1, 0, a0, b1f); LG(4); MM(0, a1, b1f); BAR;
    VM0; BAR; RD(1, 0, 0, 1, a1, b0f); LG(8); MM(1, a0, b1f); BAR;
    BAR; RD(1, 0, 1, 0, a0, b0f); LG(4); MM(0, a1, b0f); BAR;
    BAR; RD(1, 1, 0, 1, a1, b1f); LG(8); MM(1, a0, b0f); BAR;
    BAR; RD(1, 1, 1, 0, a0, b1f); LG(4); MM(0, a1, b1f); BAR;
    BAR; LG(0); MM(1, a0, b1f); BAR;

#undef STAGE_A
#undef STAGE_B
#undef VM4
#undef VM0
#undef BAR
#undef NOSTG
#undef RD
#undef LG
#undef MM

    // epilogue (R1-exact): C/D layout col=lane&15 -> n, row=(lane>>4)*4+reg -> m
    const int rbase = q << 2;
#pragma unroll
    for (int ni = 0; ni < 4; ++ni) {
        const int n = (int)tileN + (wc << 6) + (ni << 4) + fr;
        const float s = scale[n];
        const float bz = bias[n];
#pragma unroll
        for (int mi = 0; mi < 8; ++mi) {
            const size_t m = tileM + (size_t)((wr << 7) + (mi << 4) + rbase);
#pragma unroll
            for (int r = 0; r < 4; ++r)
                Out[(m + r) * N_DIM + n] = acc[mi][ni][r] * s + bz;
        }
    }
}

// ---------------- fallback GEMM (old 128x128, inline/partial convert) ----------------
template <bool XPRE, bool WPRE>
__global__ __launch_bounds__(256) void w8a16_gemm(
    const float* __restrict__ Xf, const unsigned short* __restrict__ Xh,
    const int* __restrict__ Wi, const unsigned short* __restrict__ Wh,
    const float* __restrict__ scale, const float* __restrict__ bias,
    float* __restrict__ Out)
{
    __shared__ unsigned short As[TM * BKP];
    __shared__ unsigned short Bs[TN * BKP];

    const int t = threadIdx.x;
    const int lane = t & 63;
    const int wave = t >> 6;
    const int tileM = blockIdx.y * TM;
    const int tileN = blockIdx.x * TN;
    const int wm = (wave & 1) * 64;
    const int wn = (wave >> 1) * 64;
    const int fr = lane & 15;
    const int fk = (lane >> 4) * 8;

    floatx4 acc[4][4];
#pragma unroll
    for (int mi = 0; mi < 4; ++mi)
#pragma unroll
        for (int ni = 0; ni < 4; ++ni) acc[mi][ni] = (floatx4){0.f, 0.f, 0.f, 0.f};

    for (int k0 = 0; k0 < K_DIM; k0 += BK) {
#pragma unroll
        for (int it = 0; it < 4; ++it) {
            const int c = it * 256 + t;
            const int r = c >> 3;
            const int qq = c & 7;
            if (XPRE) {
                *(int4*)(As + r * BKP + qq * 8) =
                    *(const int4*)(Xh + (size_t)(tileM + r) * K_DIM + k0 + qq * 8);
            } else {
                const float* s = Xf + (size_t)(tileM + r) * K_DIM + k0 + qq * 8;
                float4 x0 = ((const float4*)s)[0];
                float4 x1 = ((const float4*)s)[1];
                Pack16 p;
                p.h[0] = (_Float16)x0.x; p.h[1] = (_Float16)x0.y;
                p.h[2] = (_Float16)x0.z; p.h[3] = (_Float16)x0.w;
                p.h[4] = (_Float16)x1.x; p.h[5] = (_Float16)x1.y;
                p.h[6] = (_Float16)x1.z; p.h[7] = (_Float16)x1.w;
                *(int4*)(As + r * BKP + qq * 8) = p.i4;
            }
            if (WPRE) {
                *(int4*)(Bs + r * BKP + qq * 8) =
                    *(const int4*)(Wh + (size_t)(tileN + r) * K_DIM + k0 + qq * 8);
            } else {
                const int* s = Wi + (size_t)(tileN + r) * K_DIM + k0 + qq * 8;
                int4 w0 = ((const int4*)s)[0];
                int4 w1 = ((const int4*)s)[1];
                Pack16 p;
                p.h[0] = (_Float16)w0.x; p.h[1] = (_Float16)w0.y;
                p.h[2] = (_Float16)w0.z; p.h[3] = (_Float16)w0.w;
                p.h[4] = (_Float16)w1.x; p.h[5] = (_Float16)w1.y;
                p.h[6] = (_Float16)w1.z; p.h[7] = (_Float16)w1.w;
                *(int4*)(Bs + r * BKP + qq * 8) = p.i4;
            }
        }
        __syncthreads();
#pragma unroll
        for (int kh = 0; kh < 2; ++kh) {
            half8 a[4], b[4];
#pragma unroll
            for (int i = 0; i < 4; ++i)
                a[i] = *(const half8*)(const void*)(As + (wm + i * 16 + fr) * BKP + kh * 32 + fk);
#pragma unroll
            for (int i = 0; i < 4; ++i)
                b[i] = *(const half8*)(const void*)(Bs + (wn + i * 16 + fr) * BKP + kh * 32 + fk);
#pragma unroll
            for (int mi = 0; mi < 4; ++mi)
#pragma unroll
                for (int ni = 0; ni < 4; ++ni)
                    acc[mi][ni] = __builtin_amdgcn_mfma_f32_16x16x32_f16(
                        a[mi], b[ni], acc[mi][ni], 0, 0, 0);
        }
        __syncthreads();
    }

    const int rbase = (lane >> 4) * 4;
#pragma unroll
    for (int ni = 0; ni < 4; ++ni) {
        const int n = tileN + wn + ni * 16 + fr;
        const float s = scale[n];
        const float bz = bias[n];
#pragma unroll
        for (int mi = 0; mi < 4; ++mi) {
            const int m = tileM + wm + mi * 16 + rbase;
#pragma unroll
            for (int r = 0; r < 4; ++r)
                Out[(size_t)(m + r) * N_DIM + n] = acc[mi][ni][r] * s + bz;
        }
    }
}

extern "C" void kernel_launch(void* const* d_in, const int* in_sizes, int n_in,
                              void* d_out, int out_size, void* d_ws, size_t ws_size,
                              hipStream_t stream) {
    // --- resolve inputs BY SIZE (robust to pytree vs insertion ordering) ---
    const long long SZ_X = (long long)M_DIM * K_DIM;  // 33,554,432
    const long long SZ_W = (long long)N_DIM * K_DIM;  // 45,088,768
    const void *pX = nullptr, *pW = nullptr, *pS = nullptr, *pB = nullptr;
    int smallIdx[8];
    int nSmall = 0;
    for (int i = 0; i < n_in; ++i) {
        long long s = in_sizes[i];
        if (s == SZ_X && !pX) pX = d_in[i];
        else if (s == SZ_W && !pW) pW = d_in[i];
        else if (s == (long long)N_DIM && nSmall < 8) smallIdx[nSmall++] = i;
    }
    if (nSmall == 2) {
        if (smallIdx[0] == 2)      { pS = d_in[2]; pB = d_in[smallIdx[1]]; }
        else if (smallIdx[1] == 2) { pS = d_in[2]; pB = d_in[smallIdx[0]]; }
        else                       { pS = d_in[smallIdx[0]]; pB = d_in[smallIdx[1]]; }
    }
    if (!pX || !pW || !pS || !pB) { pX = d_in[0]; pW = d_in[1]; pS = d_in[2]; pB = d_in[3]; }

    const float* Xf = (const float*)pX;
    const int* Wi = (const int*)pW;
    const float* scale = (const float*)pS;
    const float* bias = (const float*)pB;
    float* Out = (float*)d_out;

    dim3 gridOld(N_DIM / TN, M_DIM / TM);  // 86 x 64
    const size_t OFF = 256;
    const size_t XH_BYTES = (size_t)SZ_X * 2;  // 67 MB fp16 x
    const size_t WH_BYTES = (size_t)SZ_W * 2;  // 90 MB fp16 w

    if (ws_size >= OFF + XH_BYTES + WH_BYTES + 64) {
        unsigned int* flags = (unsigned int*)d_ws;
        unsigned short* Xh = (unsigned short*)((char*)d_ws + OFF);
        unsigned short* Wh = (unsigned short*)((char*)d_ws + OFF + XH_BYTES);
        hipMemsetAsync(flags, 0, 4, stream);
        probe_w<<<256, 256, 0, stream>>>(Wi, flags);
        convert_x<<<(int)(SZ_X / 8 / 256), 256, 0, stream>>>(Xf, Xh);
        convert_w<<<(int)(SZ_W / 8 / 256), 256, 0, stream>>>(pW, Wh, flags);
        w8a16_gemm_8ph<<<dim3(NWG), dim3(512), 0, stream>>>(Xh, Wh, scale, bias, Out);
    } else if (ws_size >= OFF + WH_BYTES + 64) {
        unsigned int* flags = (unsigned int*)d_ws;
        unsigned short* Wh = (unsigned short*)((char*)d_ws + OFF);
        hipMemsetAsync(flags, 0, 4, stream);
        probe_w<<<256, 256, 0, stream>>>(Wi, flags);
        convert_w<<<(int)(SZ_W / 8 / 256), 256, 0, stream>>>(pW, Wh, flags);
        w8a16_gemm<false, true><<<gridOld, 256, 0, stream>>>(Xf, nullptr, Wi, Wh, scale, bias, Out);
    } else {
        w8a16_gemm<false, false><<<gridOld, 256, 0, stream>>>(Xf, nullptr, Wi, nullptr, scale, bias, Out);
    }
}